// Round 9
// baseline (326.599 us; speedup 1.0000x reference)
//
#include <hip/hip_runtime.h>
#include <math.h>
#include <stdint.h>

#define ROWS 4096
#define COLS 8192
#define KSEL 4096
#define NT 256
#define NWAVE (NT / 64)
#define PT (COLS / (4 * NT))   // float4s per thread = 8 (32 elements)
#define NBINS 1024             // bins over u in [0, 0.75); width 7.32e-4
#define WMAX 128               // window elems/row: mean ~6, P(>128) ~ 0
#define RANGE_HI 0.75f
#define LN2F 0.69314718056f

typedef float fvec4 __attribute__((ext_vector_type(4)));

// u = z + gumbel is the (monotone) selection key; bulk classification by
// 1024-bin histogram of fast-u, exact per-op-fp32-rounded fp64 chain only
// for the ~6 elements/row in bins B-1..B+1 (bitwise-proven rounds 1-4).
//
// R5: clamp bins 0/1023 (~75% of elems) counted in registers + one
// wave-reduced atomic each (bank-conflict 1.4e7 -> 7e5 cycles, verified).
//
// Falsified with counters (R6-R12): per-wave MLP depth (16 pinned in-flight
// loads, flat), occupancy (26% vs 60%, flat), intra-block 2-row pipelining
// (flat), inline fp64 sig in pass 2 (-27us regression: divergent double
// chain poisons the store loop). BW invariant ~2.2-2.3 TB/s across six
// structures. Champion codegen = compiler-interleaved loads (R4, 117us).
//
// R13 (this round): champion source + ONLY the proven-safe need2 merge --
// the scan's unique writer computes need2 itself (hist is final there) ->
// one barrier + the serial tid==0 phase deleted. Tail stays in its own
// post-drain phase (R12 taught us not to contaminate pass 2).
__device__ __forceinline__ int bin_of(float u) {
    int b = (int)(u * ((float)NBINS / RANGE_HI));
    b = b < 0 ? 0 : b;
    b = b > NBINS - 1 ? NBINS - 1 : b;
    return b;
}

__global__ __launch_bounds__(NT) void mask_topk_kernel(
    const float* __restrict__ z, const float* __restrict__ eps,
    float* __restrict__ out)
{
    __shared__ uint32_t hist[NWAVE][NBINS];   // 16 KB, one copy per wave
    __shared__ uint32_t wtot[NWAVE];
    __shared__ int      winIdx[WMAX];
    __shared__ uint32_t winSig[WMAX];
    __shared__ int      s_B, s_need2;
    __shared__ uint32_t s_wcount;

    const int row  = blockIdx.x;
    const int tid  = threadIdx.x;
    const int lane = tid & 63;
    const int wave = tid >> 6;
    const size_t rbase = (size_t)row * COLS;

    // ---- pass 1a: loads (compiler-interleaved; champion codegen) ----
    const fvec4* z4 = (const fvec4*)(z + rbase);
    const fvec4* e4 = (const fvec4*)(eps + rbase);
    fvec4 zr[PT], er[PT];
#pragma unroll
    for (int it = 0; it < PT; ++it) {
        zr[it] = z4[it * NT + tid];
        er[it] = e4[it * NT + tid];
    }

    // hist zero-init + s_wcount overlap the in-flight loads
    for (int i = tid; i < NWAVE * NBINS; i += NT) ((uint32_t*)hist)[i] = 0;
    if (tid == 0) s_wcount = 0;

    asm volatile(""
        : "+v"(zr[0]), "+v"(zr[1]), "+v"(zr[2]), "+v"(zr[3]),
          "+v"(zr[4]), "+v"(zr[5]), "+v"(zr[6]), "+v"(zr[7]),
          "+v"(er[0]), "+v"(er[1]), "+v"(er[2]), "+v"(er[3]),
          "+v"(er[4]), "+v"(er[5]), "+v"(er[6]), "+v"(er[7]));
    __syncthreads();

    // ---- pass 1b: compute u in place (zr becomes u) + per-wave histogram ----
    uint32_t cLo = 0, cHi = 0;     // register counts for the two clamp bins
#pragma unroll
    for (int it = 0; it < PT; ++it) {
        float zz[4] = {zr[it].x, zr[it].y, zr[it].z, zr[it].w};
        float ee[4] = {er[it].x, er[it].y, er[it].z, er[it].w};
        float uu[4];
#pragma unroll
        for (int j = 0; j < 4; ++j) {
            float l1 = __builtin_amdgcn_logf(ee[j]) * LN2F;   // ~log(eps) < 0
            float l2 = __builtin_amdgcn_logf(-l1) * LN2F;     // ~log(-log eps)
            uu[j] = zz[j] - l2;                               // u = z + gumbel
            int b = bin_of(uu[j]);
            if (b == 0)              ++cLo;
            else if (b == NBINS - 1) ++cHi;
            else atomicAdd(&hist[wave][b], 1u);
        }
        zr[it].x = uu[0]; zr[it].y = uu[1]; zr[it].z = uu[2]; zr[it].w = uu[3];
    }
    // wave-reduce the clamp-bin counts; one LDS atomic per wave per bin
#pragma unroll
    for (int off = 32; off >= 1; off >>= 1) {
        cLo += __shfl_down(cLo, off, 64);
        cHi += __shfl_down(cHi, off, 64);
    }
    if (lane == 0) {
        atomicAdd(&hist[wave][0],         cLo);
        atomicAdd(&hist[wave][NBINS - 1], cHi);
    }
    __syncthreads();

    // ---- per-thread 4-bin totals + shuffle-based block suffix scan ----
    const int hb = tid * (NBINS / NT);                        // 4 bins/thread
    uint32_t h[NBINS / NT];
    uint32_t cs = 0;
#pragma unroll
    for (int i = 0; i < NBINS / NT; ++i) {
        uint32_t t = 0;
#pragma unroll
        for (int c = 0; c < NWAVE; ++c) t += hist[c][hb + i];
        h[i] = t;
        cs += t;
    }
    uint32_t v = cs;                                          // wave suffix scan
#pragma unroll
    for (int off = 1; off < 64; off <<= 1) {
        uint32_t t = __shfl_down(v, off, 64);
        if (lane + off < 64) v += t;
    }
    if (lane == 0) wtot[wave] = v;
    __syncthreads();
    uint32_t above = 0;
#pragma unroll
    for (int c = 0; c < NWAVE; ++c) above += (c > wave) ? wtot[c] : 0u;
    uint32_t cum = (v + above) - cs;   // count in bins above my 4-bin chunk

    // unique writer computes B AND need2 (hist is final here) -> the
    // separate tid==0 phase and its barrier are deleted (merge proven
    // correct in R12, absmax 0).
    for (int i = NBINS / NT - 1; i >= 0; --i) {
        if (cum < KSEL && KSEL <= cum + h[i]) {
            const int Bq = hb + i;
            uint32_t hB1 = 0;
            if (Bq + 1 < NBINS) {
#pragma unroll
                for (int c = 0; c < NWAVE; ++c) hB1 += hist[c][Bq + 1];
            }
            s_B = Bq;
            // certain-1s = elements in bins > B+1 = cum - hB1
            s_need2 = KSEL - (int)(cum - hB1);
        }
        cum += h[i];
    }
    __syncthreads();
    const int B = s_B;
    const int need2 = s_need2;

    // ---- pass 2: classify from registers, NT-write, collect window ----
    fvec4* o4 = (fvec4*)(out + rbase);
#pragma unroll
    for (int it = 0; it < PT; ++it) {
        const int k = it * NT + tid;
        float uu[4] = {zr[it].x, zr[it].y, zr[it].z, zr[it].w};
        float oo[4];
#pragma unroll
        for (int j = 0; j < 4; ++j) {
            int b = bin_of(uu[j]);
            oo[j] = (b > B + 1) ? 1.0f : 0.0f;
            if (b >= B - 1 && b <= B + 1) {
                uint32_t slot = atomicAdd(&s_wcount, 1u);
                if (slot < WMAX) winIdx[slot] = k * 4 + j;
            }
        }
        fvec4 ov; ov.x = oo[0]; ov.y = oo[1]; ov.z = oo[2]; ov.w = oo[3];
        __builtin_nontemporal_store(ov, &o4[k]);
    }
    // full drain: NT stores complete before the tail's scalar overwrites
    __syncthreads();

    // ---- resolve window with exact per-op-fp32-rounded chain ----
    int w = (int)s_wcount; if (w > WMAX) w = WMAX;
    if (tid < 64) {
        for (int j = lane; j < w; j += 64) {
            int idx = winIdx[j];
            float e  = eps[rbase + idx];
            float zz = z[rbase + idx];
            float l1  = (float)log((double)e);
            float l2  = (float)log((double)(-l1));
            float g   = -l2;
            float s   = zz + g;
            float t   = s / (2.0f / 3.0f);
            float ex  = (float)exp(-(double)t);
            float sig = 1.0f / (1.0f + ex);
            winSig[j] = __float_as_uint(sig);   // sig in (0,1): uint order = float order
        }
    }
    __syncthreads();
    if (tid < 64) {
        for (int j = lane; j < w; j += 64) {
            uint32_t sj = winSig[j];
            int ij = winIdx[j];
            int rank = 0;
            for (int kk = 0; kk < w; ++kk) {
                uint32_t sk = winSig[kk];
                int ik = winIdx[kk];
                rank += (sk > sj || (sk == sj && ik < ij)) ? 1 : 0;
            }
            out[rbase + ij] = (rank < need2) ? 1.0f : 0.0f;
        }
    }
}

extern "C" void kernel_launch(void* const* d_in, const int* in_sizes, int n_in,
                              void* d_out, int out_size, void* d_ws, size_t ws_size,
                              hipStream_t stream) {
    const float* z   = (const float*)d_in[0];
    const float* eps = (const float*)d_in[1];
    float* out = (float*)d_out;
    hipLaunchKernelGGL(mask_topk_kernel, dim3(ROWS), dim3(NT), 0, stream,
                       z, eps, out);
}

// Round 10
// 317.434 us; speedup vs baseline: 1.0289x; 1.0289x over previous
//
#include <hip/hip_runtime.h>
#include <math.h>
#include <stdint.h>

#define ROWS 4096
#define COLS 8192
#define KSEL 4096
#define NT 256
#define NWAVE (NT / 64)        // 4 waves = 4 independent rows per block
#define NIT (COLS / (4 * 64))  // 32 float4-pair iterations per lane per row
#define NBINS 1024             // bins over u in [0, 0.75)
#define BPL (NBINS / 64)       // 16 bins owned per lane
#define WMAX 128               // window elems/row: mean ~6, P(>128) ~ 0
#define RANGE_HI 0.75f
#define LN2F 0.69314718056f

typedef float fvec4 __attribute__((ext_vector_type(4)));

// u = z + gumbel is the (monotone) selection key; bulk classification by
// 1024-bin histogram of fast-u, exact per-op-fp32-rounded fp64 chain only
// for the ~6 elements/row in bins B-1..B+1 (bitwise-proven rounds 1-4).
//
// Ledger: R5 clamp-bin register counts (conflicts 1.4e7->7e5, real, hidden).
// Falsified: LDS conflicts (R1), occupancy (R7: 26% vs 60% flat), forced
// load schedules (R5/R9/R13: all asm pins spilled or regressed), 2-row
// block pipeline (R11 flat), inline fp64 in pass 2 (R12: -27us).
//
// R14 (this round): ZERO-BARRIER structure -- one wave per row. The only
// untested axis is phase decorrelation: the block-wide __syncthreads
// phases (load|hist -> scan -> store -> tail) idle the memory system
// whenever all resident blocks sit in compute phases (lockstep
// generations). Now each wave owns a private hist/window; scan is a
// wave-suffix-scan; bins ride in registers as packed 16-bit (R11-proven,
// bit-identical pass-2 classification); all sync is wave-local lgkmcnt.
// Waves de-phase freely -> continuous memory demand without any forced
// schedule. Verify: VGPR ~96-112 (pb in regs, no spill), dur_us down if
// and only if the lockstep theory is right.
__device__ __forceinline__ int bin_of(float u) {
    int b = (int)(u * ((float)NBINS / RANGE_HI));
    b = b < 0 ? 0 : b;
    b = b > NBINS - 1 ? NBINS - 1 : b;
    return b;
}

__global__ __launch_bounds__(NT, 2) void mask_topk_kernel(
    const float* __restrict__ z, const float* __restrict__ eps,
    float* __restrict__ out)
{
    __shared__ uint32_t hist[NWAVE][NBINS];    // 16 KB: private 4KB per wave
    __shared__ int      winIdx[NWAVE][WMAX];   // 2 KB
    __shared__ uint32_t winSig[NWAVE][WMAX];   // 2 KB
    __shared__ uint32_t wcnt[NWAVE];
    __shared__ int      sB[NWAVE], sN2[NWAVE];

    const int tid  = threadIdx.x;
    const int lane = tid & 63;
    const int wave = tid >> 6;
    const int row  = blockIdx.x * NWAVE + wave;
    const size_t rbase = (size_t)row * COLS;

    // ---- init own hist (stride-1 across lanes: conflict-free writes) ----
#pragma unroll
    for (int i = 0; i < BPL; ++i) hist[wave][i * 64 + lane] = 0;
    if (lane == 0) wcnt[wave] = 0;
    // wave-local: writes above complete before pass-1 atomics via lgkm
    // ordering; no cross-wave dependency exists anywhere in this kernel.

    // ---- pass 1: stream row, histogram, pack 16-bit bins into registers ----
    const fvec4* z4 = (const fvec4*)(z + rbase);
    const fvec4* e4 = (const fvec4*)(eps + rbase);
    uint32_t pb[2 * NIT];          // 64 u32, statically indexed -> registers
    uint32_t cLo = 0, cHi = 0;
#pragma unroll
    for (int it = 0; it < NIT; ++it) {
        fvec4 zz4 = z4[it * 64 + lane];
        fvec4 ee4 = e4[it * 64 + lane];
        float zz[4] = {zz4.x, zz4.y, zz4.z, zz4.w};
        float ee[4] = {ee4.x, ee4.y, ee4.z, ee4.w};
        uint32_t bb[4];
#pragma unroll
        for (int j = 0; j < 4; ++j) {
            float l1 = __builtin_amdgcn_logf(ee[j]) * LN2F;   // ~log(eps) < 0
            float l2 = __builtin_amdgcn_logf(-l1) * LN2F;     // ~log(-log eps)
            float u  = zz[j] - l2;                            // u = z + gumbel
            int b = bin_of(u);
            if (b == 0)              ++cLo;
            else if (b == NBINS - 1) ++cHi;
            else atomicAdd(&hist[wave][b], 1u);
            bb[j] = (uint32_t)b;
        }
        pb[2 * it]     = bb[0] | (bb[1] << 16);
        pb[2 * it + 1] = bb[2] | (bb[3] << 16);
    }
    // clamp-bin wave reduction -> one LDS add per bin (R5 mechanism)
#pragma unroll
    for (int off = 32; off >= 1; off >>= 1) {
        cLo += __shfl_down(cLo, off, 64);
        cHi += __shfl_down(cHi, off, 64);
    }
    if (lane == 0) {
        atomicAdd(&hist[wave][0],         cLo);
        atomicAdd(&hist[wave][NBINS - 1], cHi);
    }
    // all of this wave's LDS ops drain before the scan reads
    asm volatile("s_waitcnt lgkmcnt(0)" ::: "memory");

    // ---- wave-local suffix scan; lane owns bins [lane*16, lane*16+16) ----
    // vectorized uint4 reads (8-way bank alias vs 32-way for b32 reads)
    uint32_t h[BPL]; uint32_t cs = 0;
    {
        const uint4* hv = (const uint4*)&hist[wave][lane * BPL];
#pragma unroll
        for (int q = 0; q < BPL / 4; ++q) {
            uint4 a = hv[q];
            h[4 * q + 0] = a.x; h[4 * q + 1] = a.y;
            h[4 * q + 2] = a.z; h[4 * q + 3] = a.w;
            cs += a.x + a.y + a.z + a.w;
        }
    }
    uint32_t v = cs;               // suffix-sum across lanes (high bins first)
#pragma unroll
    for (int off = 1; off < 64; off <<= 1) {
        uint32_t t = __shfl_down(v, off, 64);
        if (lane + off < 64) v += t;
    }
    uint32_t cum = v - cs;         // count in bins above my 16-bin chunk
    int Bc = -1, n2c = 0;
#pragma unroll
    for (int i = BPL - 1; i >= 0; --i) {
        if (cum < KSEL && KSEL <= cum + h[i]) {
            Bc = lane * BPL + i;
            uint32_t hB1 = (Bc + 1 < NBINS) ? hist[wave][Bc + 1] : 0;
            // certain-1s = elems in bins > B+1 = cum - hB1
            n2c = KSEL - (int)(cum - hB1);
        }
        cum += h[i];
    }
    if (Bc >= 0) { sB[wave] = Bc; sN2[wave] = n2c; }   // exactly one finder
    asm volatile("s_waitcnt lgkmcnt(0)" ::: "memory");
    const int B = sB[wave];
    const int need2 = sN2[wave];

    // ---- pass 2: classify from packed register bins, store, collect ----
    fvec4* o4 = (fvec4*)(out + rbase);
#pragma unroll
    for (int it = 0; it < NIT; ++it) {
        const int k = it * 64 + lane;
        int bb[4] = { (int)(pb[2 * it] & 0xffffu), (int)(pb[2 * it] >> 16),
                      (int)(pb[2 * it + 1] & 0xffffu), (int)(pb[2 * it + 1] >> 16) };
        float oo[4];
#pragma unroll
        for (int j = 0; j < 4; ++j) {
            oo[j] = (bb[j] > B + 1) ? 1.0f : 0.0f;
            if (bb[j] >= B - 1 && bb[j] <= B + 1) {
                uint32_t slot = atomicAdd(&wcnt[wave], 1u);
                if (slot < WMAX) winIdx[wave][slot] = k * 4 + j;
            }
        }
        fvec4 ov; ov.x = oo[0]; ov.y = oo[1]; ov.z = oo[2]; ov.w = oo[3];
        o4[k] = ov;
    }

    // ---- wave-local tail: exact chain for window, rank, scatter ----
    asm volatile("s_waitcnt lgkmcnt(0)" ::: "memory");
    int wv = (int)wcnt[wave]; if (wv > WMAX) wv = WMAX;
    for (int j = lane; j < wv; j += 64) {
        int idx = winIdx[wave][j];
        float e   = eps[rbase + idx];
        float zz  = z[rbase + idx];
        float l1  = (float)log((double)e);
        float l2  = (float)log((double)(-l1));
        float g   = -l2;
        float s   = zz + g;
        float t   = s / (2.0f / 3.0f);
        float ex  = (float)exp(-(double)t);
        float sig = 1.0f / (1.0f + ex);
        winSig[wave][j] = __float_as_uint(sig);  // (0,1): uint order = float order
    }
    // winSig visible to all lanes; float4 stores drained before the
    // scalar overwrites of the same cache lines (same-wave store order
    // is NOT guaranteed without vmcnt(0))
    asm volatile("s_waitcnt lgkmcnt(0) vmcnt(0)" ::: "memory");
    for (int j = lane; j < wv; j += 64) {
        uint32_t sj = winSig[wave][j];
        int ij = winIdx[wave][j];
        int rank = 0;
        for (int kk = 0; kk < wv; ++kk) {
            uint32_t sk = winSig[wave][kk];
            int ik = winIdx[wave][kk];
            rank += (sk > sj || (sk == sj && ik < ij)) ? 1 : 0;
        }
        out[rbase + ij] = (rank < need2) ? 1.0f : 0.0f;
    }
}

extern "C" void kernel_launch(void* const* d_in, const int* in_sizes, int n_in,
                              void* d_out, int out_size, void* d_ws, size_t ws_size,
                              hipStream_t stream) {
    const float* z   = (const float*)d_in[0];
    const float* eps = (const float*)d_in[1];
    float* out = (float*)d_out;
    hipLaunchKernelGGL(mask_topk_kernel, dim3(ROWS / NWAVE), dim3(NT), 0, stream,
                       z, eps, out);
}